// Round 1
// baseline (208.029 us; speedup 1.0000x reference)
//
#include <hip/hip_runtime.h>

// RunwayAlignmentLoss on MI355X (gfx950).
//
// Reference semantics:
//   len[b]   = count of ~target_pad_mask[b,:]           (mask is monotone 0..0 1..1)
//   idx[k]   = len[b] - 4 + k,  k = 0..3                (len in [5,120] -> idx >= 1)
//   pos[k]   = pred_abs[b, idx[k], 0:2]
//   dir[k]   = pos[k+1] - pos[k];  unit = dir / (|dir| + 1e-6)
//   rdir     = runway[b, 2:4] / (|runway[b,2:4]| + 1e-6)
//   out      = mean_b( mean_k( (1 - dot(unit, rdir))^2 ) )
//
// target_abs (d_in[1]) is UNUSED by the reference -> never read (saves 94 MB).
// Only ~35 MB of real traffic exists (mask stream + tiny gathers).

#define EPSF 1e-6f

constexpr int Bdim = 65536;
constexpr int Hdim = 120;
constexpr int WAVES_PER_BLOCK = 4;                       // 256 threads
constexpr int NBLOCKS = Bdim / WAVES_PER_BLOCK;          // 16384 blocks, 1 row per wave

__global__ __launch_bounds__(256) void runway_row_kernel(
    const float* __restrict__ pred,      // [B,120,3]
    const int*   __restrict__ mask,      // [B,120]  (bool as int32 0/1 - harness "integer -> int*")
    const float* __restrict__ runway,    // [B,4]
    float*       __restrict__ partials)  // [NBLOCKS]
{
    const int wid  = threadIdx.x >> 6;
    const int lane = threadIdx.x & 63;
    const int b    = blockIdx.x * WAVES_PER_BLOCK + wid;   // one row per wave

    // ---- phase 1: valid length via coalesced mask read + 64-bit ballot ----
    const int* mrow = mask + (size_t)b * Hdim;
    const int m0 = mrow[lane];                              // elements 0..63
    const int m1 = (lane < Hdim - 64) ? mrow[64 + lane] : 1; // elements 64..119, pad as "masked"
    const unsigned long long z0 = __ballot(m0 == 0);
    const unsigned long long z1 = __ballot(m1 == 0);
    const int len = __popcll(z0) + __popcll(z1);            // == valid_lengths[b], in [5,120]

    // ---- phase 2: lane 0 gathers 4 points + runway, computes 3 cosine terms ----
    __shared__ float sacc[WAVES_PER_BLOCK];
    if (lane == 0) {
        const float* row = pred + (size_t)b * (Hdim * 3);
        const int i0 = len - 4;

        float x[4], y[4];
#pragma unroll
        for (int k = 0; k < 4; ++k) {
            x[k] = row[(i0 + k) * 3 + 0];
            y[k] = row[(i0 + k) * 3 + 1];
        }

        const float rwx = runway[b * 4 + 2];
        const float rwy = runway[b * 4 + 3];
        const float rn  = sqrtf(rwx * rwx + rwy * rwy) + EPSF;
        const float rx  = rwx / rn;
        const float ry  = rwy / rn;

        float acc = 0.0f;
#pragma unroll
        for (int k = 0; k < 3; ++k) {
            const float dx = x[k + 1] - x[k];
            const float dy = y[k + 1] - y[k];
            const float dn = sqrtf(dx * dx + dy * dy) + EPSF;
            const float cs = (dx * rx + dy * ry) / dn;
            const float t  = 1.0f - cs;
            acc += t * t;
        }
        sacc[wid] = acc;   // sum over 3 dirs (divide by 3*B at the end)
    }

    __syncthreads();
    if (threadIdx.x == 0) {
        partials[blockIdx.x] = sacc[0] + sacc[1] + sacc[2] + sacc[3];
    }
}

__global__ __launch_bounds__(256) void runway_reduce_kernel(
    const float* __restrict__ partials,  // [NBLOCKS]
    float*       __restrict__ out)       // [1]
{
    double acc = 0.0;
    for (int i = threadIdx.x; i < NBLOCKS; i += 256)
        acc += (double)partials[i];

    // wave reduce (64 lanes)
#pragma unroll
    for (int off = 32; off > 0; off >>= 1)
        acc += __shfl_down(acc, off);

    __shared__ double sd[4];
    if ((threadIdx.x & 63) == 0) sd[threadIdx.x >> 6] = acc;
    __syncthreads();
    if (threadIdx.x == 0) {
        const double total = sd[0] + sd[1] + sd[2] + sd[3];
        out[0] = (float)(total / (3.0 * (double)Bdim));   // mean over 3 dirs, mean over B, SCALE=1
    }
}

extern "C" void kernel_launch(void* const* d_in, const int* in_sizes, int n_in,
                              void* d_out, int out_size, void* d_ws, size_t ws_size,
                              hipStream_t stream) {
    const float* pred   = (const float*)d_in[0];   // pred_abs  [B,120,3] f32
    // d_in[1] = target_abs — unused by the reference, deliberately not read
    const int*   mask   = (const int*)d_in[2];     // target_pad_mask [B,120] (bool -> int32)
    const float* runway = (const float*)d_in[3];   // runway [B,4] f32
    float* out = (float*)d_out;

    float* partials = (float*)d_ws;                // 16384 floats = 64 KB scratch

    runway_row_kernel<<<NBLOCKS, 256, 0, stream>>>(pred, mask, runway, partials);
    runway_reduce_kernel<<<1, 256, 0, stream>>>(partials, out);
}

// Round 2
// 198.150 us; speedup vs baseline: 1.0499x; 1.0499x over previous
//
#include <hip/hip_runtime.h>

// RunwayAlignmentLoss on MI355X (gfx950).
//
// len[b] = count of zeros in target_pad_mask[b,:]  (monotone mask, len in [5,120])
// 4 trailing pred points -> 3 dirs -> cos vs normalized runway[:,2:4] ->
// mean_b mean_k (1-cos)^2.
//
// target_abs (d_in[1]) is UNUSED by the reference -> never read (saves 94 MB).
// Real traffic ~ 40 MB (mask stream 31.5 MB + gather cache lines ~9 MB).

#define EPSF 1e-6f

constexpr int Bdim = 65536;
constexpr int Hdim = 120;
constexpr int WAVES_PER_BLOCK = 4;                        // 256 threads
constexpr int ROWS_PER_WAVE   = 8;
constexpr int ROWS_PER_BLOCK  = WAVES_PER_BLOCK * ROWS_PER_WAVE;  // 32
constexpr int NBLOCKS         = Bdim / ROWS_PER_BLOCK;            // 2048

__global__ __launch_bounds__(256) void runway_row_kernel(
    const float* __restrict__ pred,      // [B,120,3] f32
    const int*   __restrict__ mask,      // [B,120]   bool as int32 0/1 (verified: absmax=0)
    const float* __restrict__ runway,    // [B,4]     f32
    float*       __restrict__ partials)  // [NBLOCKS]
{
    const int wid  = threadIdx.x >> 6;
    const int lane = threadIdx.x & 63;

    float wacc = 0.0f;   // meaningful on lane 0 only

#pragma unroll
    for (int r = 0; r < ROWS_PER_WAVE; ++r) {
        // block's 4 waves read 4 contiguous rows each iteration -> streaming
        const int b = blockIdx.x * ROWS_PER_BLOCK + r * WAVES_PER_BLOCK + wid;

        // ---- valid length: coalesced mask row read + 64-bit ballot ----
        const int* mrow = mask + (size_t)b * Hdim;
        const int m0 = mrow[lane];                                // 0..63
        const int m1 = (lane < Hdim - 64) ? mrow[64 + lane] : 1;  // 64..119
        const int len = __popcll(__ballot(m0 == 0)) + __popcll(__ballot(m1 == 0));

        // ---- lane 0: gather 4 tail points + runway dir, 3 cosine terms ----
        if (lane == 0) {
            const float* row = pred + (size_t)b * (Hdim * 3) + (size_t)(len - 4) * 3;
            // 12 consecutive floats starting at (len-4)*3: x,y,(z),...
            const float x0 = row[0], y0 = row[1];
            const float x1 = row[3], y1 = row[4];
            const float x2 = row[6], y2 = row[7];
            const float x3 = row[9], y3 = row[10];

            const float rwx = runway[b * 4 + 2];
            const float rwy = runway[b * 4 + 3];
            const float rn  = sqrtf(rwx * rwx + rwy * rwy) + EPSF;
            const float rx  = rwx / rn;
            const float ry  = rwy / rn;

            float dx, dy, dn, cs, t;
            dx = x1 - x0; dy = y1 - y0;
            dn = sqrtf(dx * dx + dy * dy) + EPSF;
            cs = (dx * rx + dy * ry) / dn; t = 1.0f - cs; wacc += t * t;

            dx = x2 - x1; dy = y2 - y1;
            dn = sqrtf(dx * dx + dy * dy) + EPSF;
            cs = (dx * rx + dy * ry) / dn; t = 1.0f - cs; wacc += t * t;

            dx = x3 - x2; dy = y3 - y2;
            dn = sqrtf(dx * dx + dy * dy) + EPSF;
            cs = (dx * rx + dy * ry) / dn; t = 1.0f - cs; wacc += t * t;
        }
    }

    __shared__ float sacc[WAVES_PER_BLOCK];
    if (lane == 0) sacc[wid] = wacc;
    __syncthreads();
    if (threadIdx.x == 0)
        partials[blockIdx.x] = sacc[0] + sacc[1] + sacc[2] + sacc[3];
}

__global__ __launch_bounds__(256) void runway_reduce_kernel(
    const float* __restrict__ partials,  // [NBLOCKS]
    float*       __restrict__ out)       // [1]
{
    double acc = 0.0;
    for (int i = threadIdx.x; i < NBLOCKS; i += 256)
        acc += (double)partials[i];

#pragma unroll
    for (int off = 32; off > 0; off >>= 1)
        acc += __shfl_down(acc, off);

    __shared__ double sd[4];
    if ((threadIdx.x & 63) == 0) sd[threadIdx.x >> 6] = acc;
    __syncthreads();
    if (threadIdx.x == 0) {
        const double total = sd[0] + sd[1] + sd[2] + sd[3];
        out[0] = (float)(total / (3.0 * (double)Bdim));  // mean over 3 dirs & B, SCALE=1
    }
}

extern "C" void kernel_launch(void* const* d_in, const int* in_sizes, int n_in,
                              void* d_out, int out_size, void* d_ws, size_t ws_size,
                              hipStream_t stream) {
    const float* pred   = (const float*)d_in[0];   // pred_abs [B,120,3]
    // d_in[1] = target_abs — unused by the reference, deliberately not read
    const int*   mask   = (const int*)d_in[2];     // target_pad_mask [B,120]
    const float* runway = (const float*)d_in[3];   // runway [B,4]
    float* out = (float*)d_out;

    float* partials = (float*)d_ws;                // 2048 floats = 8 KB scratch

    runway_row_kernel<<<NBLOCKS, 256, 0, stream>>>(pred, mask, runway, partials);
    runway_reduce_kernel<<<1, 256, 0, stream>>>(partials, out);
}

// Round 4
// 185.284 us; speedup vs baseline: 1.1228x; 1.0694x over previous
//
#include <hip/hip_runtime.h>

// RunwayAlignmentLoss on MI355X (gfx950).
//
// len[b] = count of zeros in target_pad_mask[b,:]  (monotone mask, len in [5,120])
// 4 trailing pred_abs points -> 3 dirs -> cos vs normalized runway[:,2:4] ->
// mean_b mean_k (1-cos)^2.
//
// target_abs (d_in[1]) is UNUSED by the reference -> never read (saves 94 MB).
// Real traffic ~ 45 MB (mask stream 31.5 MB + gather cache lines).
//
// Structure: phase A = per-row int4 mask load + 4 ballots (wave-uniform len,
// lane r captures row r's len). phase B = lanes 0-7 gather their own row's
// tail points + runway dir CONCURRENTLY (9 VMEM instrs @ 8 active lanes vs
// ~80 @ 1 lane in the round-1 version), math once with 8 lanes, shfl_xor
// reduce. VMEM/VALU instruction count per wave drops ~8x.

#define EPSF 1e-6f

constexpr int Bdim = 65536;
constexpr int Hdim = 120;                                 // 480 B/row, 16B-aligned
constexpr int WAVES_PER_BLOCK = 4;                        // 256 threads
constexpr int ROWS_PER_WAVE   = 8;
constexpr int ROWS_PER_BLOCK  = WAVES_PER_BLOCK * ROWS_PER_WAVE;  // 32
constexpr int NBLOCKS         = Bdim / ROWS_PER_BLOCK;            // 2048

__global__ __launch_bounds__(256) void runway_row_kernel(
    const float* __restrict__ pred,      // [B,120,3] f32
    const int*   __restrict__ mask,      // [B,120]   bool as int32 0/1 (verified: absmax=0)
    const float* __restrict__ runway,    // [B,4]     f32
    float*       __restrict__ partials)  // [NBLOCKS]
{
    const int wid  = threadIdx.x >> 6;
    const int lane = threadIdx.x & 63;
    const int base = blockIdx.x * ROWS_PER_BLOCK;

    // ---- phase A: 8 rows per wave; one int4 mask load + 4 ballots per row.
    // ballot results are wave-uniform -> lane r keeps row r's len.
    int mylen = 0;
#pragma unroll
    for (int r = 0; r < ROWS_PER_WAVE; ++r) {
        const int b = base + r * WAVES_PER_BLOCK + wid;   // 4 waves read 4 consecutive rows
        const int4* mrow = (const int4*)(mask + (size_t)b * Hdim);  // 16B-aligned
        int4 mv = make_int4(1, 1, 1, 1);
        if (lane < Hdim / 4) mv = mrow[lane];             // lanes 0..29 cover 120 ints
        const int len = __popcll(__ballot(mv.x == 0))
                      + __popcll(__ballot(mv.y == 0))
                      + __popcll(__ballot(mv.z == 0))
                      + __popcll(__ballot(mv.w == 0));
        if (lane == r) mylen = len;                       // v_cndmask
    }

    // ---- phase B: lanes 0..7 gather their own row concurrently ----
    float acc = 0.0f;
    if (lane < ROWS_PER_WAVE) {
        const int b = base + lane * WAVES_PER_BLOCK + wid;
        const float* row = pred + (size_t)b * (Hdim * 3) + (size_t)(mylen - 4) * 3;
        // 8 needed floats of the 12 consecutive: x,y at strides of 3
        const float x0 = row[0], y0 = row[1];
        const float x1 = row[3], y1 = row[4];
        const float x2 = row[6], y2 = row[7];
        const float x3 = row[9], y3 = row[10];

        const float2 rw = *(const float2*)(runway + (size_t)b * 4 + 2);  // 8B-aligned
        const float rn  = sqrtf(rw.x * rw.x + rw.y * rw.y) + EPSF;
        const float rx  = rw.x / rn;
        const float ry  = rw.y / rn;

        float dx, dy, dn, cs, t;
        dx = x1 - x0; dy = y1 - y0;
        dn = sqrtf(dx * dx + dy * dy) + EPSF;
        cs = (dx * rx + dy * ry) / dn; t = 1.0f - cs; acc += t * t;

        dx = x2 - x1; dy = y2 - y1;
        dn = sqrtf(dx * dx + dy * dy) + EPSF;
        cs = (dx * rx + dy * ry) / dn; t = 1.0f - cs; acc += t * t;

        dx = x3 - x2; dy = y3 - y2;
        dn = sqrtf(dx * dx + dy * dy) + EPSF;
        cs = (dx * rx + dy * ry) / dn; t = 1.0f - cs; acc += t * t;
    }

    // reduce lanes 0..7 (lanes 8+ hold 0.0 -> harmless in their own 8-groups)
    acc += __shfl_xor(acc, 1);
    acc += __shfl_xor(acc, 2);
    acc += __shfl_xor(acc, 4);

    __shared__ float sacc[WAVES_PER_BLOCK];
    if (lane == 0) sacc[wid] = acc;
    __syncthreads();
    if (threadIdx.x == 0)
        partials[blockIdx.x] = sacc[0] + sacc[1] + sacc[2] + sacc[3];
}

__global__ __launch_bounds__(256) void runway_reduce_kernel(
    const float* __restrict__ partials,  // [NBLOCKS]
    float*       __restrict__ out)       // [1]
{
    double acc = 0.0;
    for (int i = threadIdx.x; i < NBLOCKS; i += 256)
        acc += (double)partials[i];

#pragma unroll
    for (int off = 32; off > 0; off >>= 1)
        acc += __shfl_down(acc, off);

    __shared__ double sd[4];
    if ((threadIdx.x & 63) == 0) sd[threadIdx.x >> 6] = acc;
    __syncthreads();
    if (threadIdx.x == 0) {
        const double total = sd[0] + sd[1] + sd[2] + sd[3];
        out[0] = (float)(total / (3.0 * (double)Bdim));  // mean over 3 dirs & B, SCALE=1
    }
}

extern "C" void kernel_launch(void* const* d_in, const int* in_sizes, int n_in,
                              void* d_out, int out_size, void* d_ws, size_t ws_size,
                              hipStream_t stream) {
    const float* pred   = (const float*)d_in[0];   // pred_abs [B,120,3]
    // d_in[1] = target_abs — unused by the reference, deliberately not read
    const int*   mask   = (const int*)d_in[2];     // target_pad_mask [B,120]
    const float* runway = (const float*)d_in[3];   // runway [B,4]
    float* out = (float*)d_out;

    float* partials = (float*)d_ws;                // 2048 floats = 8 KB scratch

    runway_row_kernel<<<NBLOCKS, 256, 0, stream>>>(pred, mask, runway, partials);
    runway_reduce_kernel<<<1, 256, 0, stream>>>(partials, out);
}